// Round 7
// baseline (398.458 us; speedup 1.0000x reference)
//
#include <hip/hip_runtime.h>
#include <math.h>

#define NT 2560
#define DF 32
#define NB 4
#define SELF_EPS 0.5f
#define MS 8                 // m-split across blocks (split-K style)
#define MROWS (NT / MS)      // 320 m rows per slice
#define MT 64                // m tile
#define MITERS (MROWS / MT)  // 5
#define TN 64                // n rows per block (4 waves x 16)

typedef __attribute__((ext_vector_type(8))) short bf16x8;
typedef __attribute__((ext_vector_type(4))) float f32x4;

__device__ __forceinline__ unsigned short f2bf(float f) {
    unsigned u = __builtin_bit_cast(unsigned, f);
    u += 0x7fffu + ((u >> 16) & 1u);   // RNE
    return (unsigned short)(u >> 16);
}
__device__ __forceinline__ float fast_rcp(float x) {
#if __has_builtin(__builtin_amdgcn_rcpf)
    return __builtin_amdgcn_rcpf(x);
#else
    return 1.0f / x;
#endif
}
__device__ __forceinline__ float fast_exp2(float x) {
#if __has_builtin(__builtin_amdgcn_exp2f)
    return __builtin_amdgcn_exp2f(x);
#else
    return exp2f(x);
#endif
}
// tanh(relu(x)) = 1 - 2/(exp2(2*log2e*x)+1) for x>=0
__device__ __forceinline__ float tanh_relu(float x) {
    float m = fmaxf(x, 0.0f);
    float e = fast_exp2(m * 2.885390082f);
    return 1.0f - 2.0f * fast_rcp(e + 1.0f);
}
__device__ __forceinline__ float elu(float x) {
    return x > 0.f ? x : fast_exp2(x * 1.442695041f) - 1.f;
}

// ---------------------------------------------------------------------------
// prep (R2-verbatim + flag zeroing): X fp32 -> Xb bf16 [B][NT][32],
// XT bf16 [B][32][NT]; zero the 320 completion flags (ws is re-poisoned).
// ---------------------------------------------------------------------------
__global__ __launch_bounds__(256, 4)
void prep(const float* __restrict__ X,
          unsigned short* __restrict__ Xb, unsigned short* __restrict__ XT,
          int* __restrict__ flags)
{
    const int t = threadIdx.x;
    if (t == 0) flags[blockIdx.x] = 0;   // 320 blocks cover both layers' flags
    __shared__ float sT[32][33];
    const int tile = blockIdx.x;
    const int b = tile / 80, n0 = (tile % 80) * 32;
    const int row = t >> 3, c4 = (t & 7) * 4;
    const size_t rbase = ((size_t)(b * NT + n0 + row)) * DF + c4;
    const float4 v = *(const float4*)(X + rbase);
    unsigned p0 = (unsigned)f2bf(v.x) | ((unsigned)f2bf(v.y) << 16);
    unsigned p1 = (unsigned)f2bf(v.z) | ((unsigned)f2bf(v.w) << 16);
    *(uint2*)(Xb + rbase) = make_uint2(p0, p1);
    sT[row][c4 + 0] = v.x; sT[row][c4 + 1] = v.y;
    sT[row][c4 + 2] = v.z; sT[row][c4 + 3] = v.w;
    __syncthreads();
    const int d = t >> 3, nq = (t & 7) * 4;
    unsigned q0 = (unsigned)f2bf(sT[nq + 0][d]) | ((unsigned)f2bf(sT[nq + 1][d]) << 16);
    unsigned q1 = (unsigned)f2bf(sT[nq + 2][d]) | ((unsigned)f2bf(sT[nq + 3][d]) << 16);
    *(uint2*)(XT + ((size_t)(b * DF + d)) * NT + n0 + nq) = make_uint2(q0, q1);
}

// ---------------------------------------------------------------------------
// fused main: R2-structure score+agg (shared staging, conflict-free strides
// 40/72, 1280 blocks, 5 blocks/CU) + split-K tail epilogue in the last
// arriving slice-block per (n-tile, batch) group.
// LDS map (19200 B + flag):
//   [0,     9216)  S: per-wave 16n x 72 shorts at w*2304   (tail: sAgg 64x33 f32)
//   [9216, 14336)  Xm: 64m x 40 shorts                     (tail: sW 32x36 f32)
//   [14336,18944)  Ht: 32d x 72 shorts                     (tail: sN 32x36 f32)
// ---------------------------------------------------------------------------
__global__ __launch_bounds__(256, 5)
void gsage_fused(const unsigned short* __restrict__ Xb,   // [B][NT][32] bf16
                 const unsigned short* __restrict__ HT,   // [B][32][NT] bf16
                 const float* __restrict__ Hin,           // [B][NT][32] fp32
                 const float* __restrict__ Wsl, const float* __restrict__ Wnl,
                 const float* __restrict__ bl,
                 float* __restrict__ part,                // [MS][B][NT][32] fp32
                 int* __restrict__ flag,                  // [160] this layer
                 float* __restrict__ Hout,                // [B][NT][32] fp32
                 unsigned short* __restrict__ HTout)      // [B][32][NT] or null
{
    __shared__ __align__(16) char smem[19200];
    __shared__ int sLast;
    unsigned short* Ss  = (unsigned short*)smem;
    unsigned short* XmL = (unsigned short*)(smem + 9216);
    unsigned short* HtL = (unsigned short*)(smem + 14336);

    const int t = threadIdx.x;
    const int w = t >> 6, lane = t & 63;
    const int q = lane >> 4, c = lane & 15;
    const int n0 = blockIdx.x * TN;
    const int slice = blockIdx.y;
    const int mbase = slice * MROWS;
    const int b = blockIdx.z;
    const size_t xbase = (size_t)b * NT * DF;
    const size_t tbase = (size_t)b * DF * NT;

    // score B-frag: Xn[n=n0+w*16+c][k=q*8..+7], loop-invariant
    const bf16x8 bfn = *(const bf16x8*)(Xb + xbase + (size_t)(n0 + w * 16 + c) * DF + q * 8);

    f32x4 acc0 = {0.f, 0.f, 0.f, 0.f};
    f32x4 acc1 = {0.f, 0.f, 0.f, 0.f};

    const int xrow = t >> 2, xseg = t & 3;   // Xm stage: 64 rows, 4 x 16B
    const int hrow = t >> 3, hseg = t & 7;   // HT stage: 32 rows, 8 x 16B

    uint4 xv = *(const uint4*)(Xb + xbase + (size_t)(mbase + xrow) * DF + xseg * 8);
    uint4 hv = *(const uint4*)(HT + tbase + (size_t)hrow * NT + mbase + hseg * 8);

    unsigned short* SsW = Ss + w * 1152;   // 16 x 72

    for (int it = 0; it < MITERS; ++it) {
        const int m0 = mbase + it * MT;
        __syncthreads();                       // prior iter done reading LDS
        *(uint4*)(XmL + xrow * 40 + xseg * 8) = xv;
        *(uint4*)(HtL + hrow * 72 + hseg * 8) = hv;
        if (it + 1 < MITERS) {
            const int m1 = m0 + MT;
            xv = *(const uint4*)(Xb + xbase + (size_t)(m1 + xrow) * DF + xseg * 8);
            hv = *(const uint4*)(HT + tbase + (size_t)hrow * NT + m1 + hseg * 8);
        }
        __syncthreads();                       // tiles staged

        // ---- scores: lane holds S[n=c][m = m0 + t4*16 + q*4 + r] ----
        #pragma unroll
        for (int t4 = 0; t4 < 4; ++t4) {
            const bf16x8 af = *(const bf16x8*)(XmL + (t4 * 16 + c) * 40 + q * 8);
            const f32x4 zero = {0.f, 0.f, 0.f, 0.f};
            f32x4 st = __builtin_amdgcn_mfma_f32_16x16x32_bf16(af, bfn, zero, 0, 0, 0);
            float v0 = tanh_relu(st[0]);
            float v1 = tanh_relu(st[1]);
            float v2 = tanh_relu(st[2]);
            float v3 = tanh_relu(st[3]);
            if ((n0 + w * 16 == m0 + t4 * 16) && (q == (c >> 2))) {   // diag tile
                const int r = c & 3;
                v0 += (r == 0) ? SELF_EPS : 0.f;
                v1 += (r == 1) ? SELF_EPS : 0.f;
                v2 += (r == 2) ? SELF_EPS : 0.f;
                v3 += (r == 3) ? SELF_EPS : 0.f;
            }
            unsigned p0 = (unsigned)f2bf(v0) | ((unsigned)f2bf(v1) << 16);
            unsigned p1 = (unsigned)f2bf(v2) | ((unsigned)f2bf(v3) << 16);
            *(uint2*)(SsW + c * 72 + t4 * 16 + q * 4) = make_uint2(p0, p1);
        }
        asm volatile("s_waitcnt lgkmcnt(0)" ::: "memory");  // S visible wave-wide

        // ---- agg: acc[n][d] += S[n][m] * H[m][d] ----
        #pragma unroll
        for (int kc = 0; kc < 2; ++kc) {
            const bf16x8 sf  = *(const bf16x8*)(SsW + c * 72 + kc * 32 + q * 8);
            const bf16x8 h0  = *(const bf16x8*)(HtL + c * 72 + kc * 32 + q * 8);
            const bf16x8 h1v = *(const bf16x8*)(HtL + (16 + c) * 72 + kc * 32 + q * 8);
            acc0 = __builtin_amdgcn_mfma_f32_16x16x32_bf16(sf, h0, acc0, 0, 0, 0);
            acc1 = __builtin_amdgcn_mfma_f32_16x16x32_bf16(sf, h1v, acc1, 0, 0, 0);
        }
    }

    // ---- store this slice's private partial (plain stores) ----
    float* pp = part + ((size_t)slice * NB) * NT * DF + xbase
                     + (size_t)(n0 + w * 16 + q * 4) * DF + c;
    #pragma unroll
    for (int r = 0; r < 4; ++r) {
        pp[(size_t)r * DF]      = acc0[r];
        pp[(size_t)r * DF + 16] = acc1[r];
    }

    // ---- split-K tail: last arriving slice-block does the epilogue ----
    __threadfence();                           // release partial stores
    if (t == 0)
        sLast = (atomicAdd(flag + blockIdx.z * 40 + blockIdx.x, 1) == MS - 1);
    __syncthreads();
    if (!sLast) return;
    __threadfence();                           // acquire other slices' stores

    float* sAgg = (float*)smem;                // [64][33] fp32 (8448 <= 9216)
    float* sW   = (float*)(smem + 9216);       // [32][36] fp32 (4608 <= 5120)
    float* sN   = (float*)(smem + 14336);      // [32][36] fp32 (4608 <= 4608)

    const int row = t >> 2, ds0 = (t & 3) * 8;
    {   // reduce 8 partials: thread covers (row, d = ds0..ds0+8)
        float a[8];
        #pragma unroll
        for (int j = 0; j < 8; ++j) a[j] = 0.f;
        #pragma unroll
        for (int s = 0; s < MS; ++s) {
            const float* p = part + ((size_t)s * NB + b) * NT * DF
                                  + (size_t)(n0 + row) * DF + ds0;
            const float4 u0 = *(const float4*)(p);
            const float4 u1 = *(const float4*)(p + 4);
            a[0] += u0.x; a[1] += u0.y; a[2] += u0.z; a[3] += u0.w;
            a[4] += u1.x; a[5] += u1.y; a[6] += u1.z; a[7] += u1.w;
        }
        #pragma unroll
        for (int j = 0; j < 8; ++j) sAgg[row * 33 + ds0 + j] = a[j];
    }
    {   // stage weights 32x32 each
        const int k = t >> 3, c4 = (t & 7) * 4;
        const float4 w0 = *(const float4*)(Wsl + k * DF + c4);
        const float4 w1 = *(const float4*)(Wnl + k * DF + c4);
        *(float4*)&sW[k * 36 + c4] = w0;
        *(float4*)&sN[k * 36 + c4] = w1;
    }
    __syncthreads();

    // ---- epilogue: z = elu(h·Ws + agg·Wn + b), 8 outputs per thread ----
    float z[8];
    #pragma unroll
    for (int j = 0; j < 8; ++j) z[j] = bl[ds0 + j];
    const float* hrow2 = Hin + ((size_t)b * NT + n0 + row) * DF;
    #pragma unroll
    for (int k = 0; k < DF; ++k) {
        const float hk = hrow2[k];
        const float ak = sAgg[row * 33 + k];
        #pragma unroll
        for (int j = 0; j < 8; ++j)
            z[j] += hk * sW[k * 36 + ds0 + j] + ak * sN[k * 36 + ds0 + j];
    }
    #pragma unroll
    for (int j = 0; j < 8; ++j) z[j] = elu(z[j]);
    {
        float* orow = Hout + ((size_t)b * NT + n0 + row) * DF + ds0;
        *(float4*)orow       = make_float4(z[0], z[1], z[2], z[3]);
        *(float4*)(orow + 4) = make_float4(z[4], z[5], z[6], z[7]);
    }

    if (HTout != nullptr) {   // uniform branch: emit transposed bf16 copy
        __syncthreads();      // sAgg reads done; reuse as sOut
        #pragma unroll
        for (int j = 0; j < 8; ++j) sAgg[row * 33 + ds0 + j] = z[j];
        __syncthreads();
        const int d = t >> 3, mp = (t & 7) * 8;
        unsigned pk[4];
        #pragma unroll
        for (int i = 0; i < 4; ++i)
            pk[i] = (unsigned)f2bf(sAgg[(mp + 2 * i) * 33 + d])
                  | ((unsigned)f2bf(sAgg[(mp + 2 * i + 1) * 33 + d]) << 16);
        *(uint4*)(HTout + ((size_t)b * DF + d) * NT + n0 + mp) =
            make_uint4(pk[0], pk[1], pk[2], pk[3]);
    }
}

extern "C" void kernel_launch(void* const* d_in, const int* in_sizes, int n_in,
                              void* d_out, int out_size, void* d_ws, size_t ws_size,
                              hipStream_t stream) {
    const float* X  = (const float*)d_in[0];
    const float* Ws = (const float*)d_in[1];   // [2][32][32]
    const float* Wn = (const float*)d_in[2];   // [2][32][32]
    const float* bv = (const float*)d_in[3];   // [2][32]
    float* out = (float*)d_out;

    char* ws = (char*)d_ws;
    float* part = (float*)ws;                                // 10,485,760 B
    float* h1   = part + (size_t)MS * NB * NT * DF;          // 1,310,720 B
    unsigned short* Xb  = (unsigned short*)(ws + 11796480);  // 655,360 B
    unsigned short* XT  = Xb + (size_t)NB * NT * DF;         // 655,360 B
    unsigned short* H1T = XT + (size_t)NB * NT * DF;         // 655,360 B
    int* flags = (int*)(ws + 13762560);                      // 320 ints

    prep<<<320, 256, 0, stream>>>(X, Xb, XT, flags);

    dim3 g(NT / TN, MS, NB);   // 40 x 8 x 4 = 1280 blocks = 5 blocks/CU
    gsage_fused<<<g, 256, 0, stream>>>(Xb, XT, X, Ws, Wn, bv,
                                       part, flags, h1, H1T);
    gsage_fused<<<g, 256, 0, stream>>>(Xb, H1T, h1, Ws + DF * DF, Wn + DF * DF,
                                       bv + DF, part, flags + 160, out, nullptr);
}